// Round 6
// baseline (64683.075 us; speedup 1.0000x reference)
//
#include <hip/hip_runtime.h>

#define T_STEPS 16384
#define HID     1000
#define NB      250      // workgroups; each owns 4 hidden units (wave w <-> unit 4*bid+w)
#define NTH     256      // 4 waves
#define RS      1024     // LDS row stride: [W_hh(1000) | W_ih(18) | b(1) | 0 x5]
#define EPAR    1024     // u64 entries per parity buffer (1000 used)
#define SLEEPQ  8        // s_sleep(8) = 512 cy backoff between failed poll rounds

typedef unsigned int       uint32;
typedef unsigned long long u64;

__device__ __forceinline__ u64 ag_load(const u64* p) {
  return __hip_atomic_load(p, __ATOMIC_RELAXED, __HIP_MEMORY_SCOPE_AGENT);
}
__device__ __forceinline__ void ag_store(u64* p, u64 v) {
  __hip_atomic_store(p, v, __ATOMIC_RELAXED, __HIP_MEMORY_SCOPE_AGENT);
}
__device__ __forceinline__ u64 pack_entry(float v, uint32 seq) {
  return ((u64)seq << 32) | (u64)__float_as_uint(v);
}

// Dense-entry gather with backoff. Entries ep[0..999] = {val lo32, seq hi32}.
// Thread tid polls {tid, tid+256, tid+512, tid+768}. First attempt immediate;
// failed rounds back off s_sleep(SLEEPQ) to keep per-LLC-line request rate
// below the service rate (250 WGs all poll every line — rate, not volume,
// is the limiter). Terminates: entry seq==tgt is only overwritten at tgt+2,
// which requires this WG to have consumed tgt (2-parity argument).
__device__ __forceinline__ void gather_dense(const u64* ep, uint32 tgt, int tid,
                                             float* vb, bool relu) {
  uint32 pend = (768 + tid < HID) ? 0xFu : 0x7u;
  for (;;) {
    u64 e0 = 0, e1 = 0, e2 = 0, e3 = 0;
    if (pend & 1u) e0 = ag_load(ep + tid);
    if (pend & 2u) e1 = ag_load(ep + 256 + tid);
    if (pend & 4u) e2 = ag_load(ep + 512 + tid);
    if (pend & 8u) e3 = ag_load(ep + 768 + tid);
    uint32 got = 0;
    if ((pend & 1u) && (uint32)(e0 >> 32) == tgt) {
      float v = __uint_as_float((uint32)e0);
      vb[tid] = relu ? fmaxf(v, 0.f) : v;  got |= 1u;
    }
    if ((pend & 2u) && (uint32)(e1 >> 32) == tgt) {
      float v = __uint_as_float((uint32)e1);
      vb[256 + tid] = relu ? fmaxf(v, 0.f) : v;  got |= 2u;
    }
    if ((pend & 4u) && (uint32)(e2 >> 32) == tgt) {
      float v = __uint_as_float((uint32)e2);
      vb[512 + tid] = relu ? fmaxf(v, 0.f) : v;  got |= 4u;
    }
    if ((pend & 8u) && (uint32)(e3 >> 32) == tgt) {
      float v = __uint_as_float((uint32)e3);
      vb[768 + tid] = relu ? fmaxf(v, 0.f) : v;  got |= 8u;
    }
    pend &= ~got;
    if (!pend) break;
    __builtin_amdgcn_s_sleep(SLEEPQ);
  }
}

__global__ __launch_bounds__(NTH) void lstm_mlp_kernel(
    const float* __restrict__ x,    const float* __restrict__ h0,
    const float* __restrict__ c0,   const float* __restrict__ W_ih,
    const float* __restrict__ W_hh, const float* __restrict__ b_ih,
    const float* __restrict__ b_hh,
    const float* __restrict__ W1, const float* __restrict__ b1,
    const float* __restrict__ W2, const float* __restrict__ b2,
    const float* __restrict__ W3, const float* __restrict__ b3,
    const float* __restrict__ W4, const float* __restrict__ b4,
    const float* __restrict__ Wo, const float* __restrict__ bo,
    u64* __restrict__ ent, float* __restrict__ out)
{
  __shared__ __align__(16) float lds_W[16 * RS];   // 64 KB: 16 LSTM gate rows
  __shared__ __align__(16) float lds_v[2][RS];     // parity-double-buffered v
  __shared__ float lds_log[3];

  const int tid   = threadIdx.x;
  const int bid   = blockIdx.x;
  const int wv    = tid >> 6;     // wave 0..3 <-> hidden unit 4*bid+wv
  const int lane  = tid & 63;
  const int lane4 = lane * 4;
  const bool hx   = (tid < 18);

  // -------- stage 16 LSTM gate rows into LDS (W_hh read from HBM once) ----------
  for (int rr = 0; rr < 16; ++rr) {               // rr = w*4 + g
    const int w = rr >> 2, g = rr & 3;
    const int grow = g * HID + 4 * bid + w;       // global gate row in [0,4000)
    const float* src = W_hh + (size_t)grow * HID;
    float* dst = lds_W + rr * RS;
    for (int k4 = tid; k4 < 250; k4 += NTH)
      *(float4*)&dst[k4 * 4] = *(const float4*)&src[k4 * 4];
    if (tid < 24) {                               // tail [1000,1024)
      float v = 0.f;
      if (tid < 18)       v = W_ih[(size_t)grow * 18 + tid];
      else if (tid == 18) v = b_ih[grow] + b_hh[grow];
      dst[1000 + tid] = v;
    }
  }
  if (tid < 24) {                                 // both buffers: bias-one + zero pad
    lds_v[0][1000 + tid] = (tid == 18) ? 1.f : 0.f;
    lds_v[1][1000 + tid] = (tid == 18) ? 1.f : 0.f;
  }

  float c_state = 0.f;
  if (lane == 0) c_state = c0[4 * bid + wv];

  float xval = 0.f;
  if (hx) xval = x[tid];                          // x for step 1
  __syncthreads();

  // -------- 16384-step recurrence ------------------------------------------------
  for (int t = 1; t <= T_STEPS; ++t) {
    float* vb = lds_v[(t - 1) & 1];               // holds [h_{t-1} | x_t | 1 | 0]

    if (hx) vb[1000 + tid] = xval;                // x_t staged (prefetched last step)

    if (t == 1) {
      if (tid < NB) *(float4*)&vb[4 * tid] = *(const float4*)&h0[4 * tid];
    } else {
      gather_dense(ent + ((t - 1) & 1) * EPAR, (uint32)(t - 1), tid, vb, false);
    }

    if (hx && t < T_STEPS) xval = x[(size_t)t * 18 + tid];  // prefetch next x;
    // waitcnt for it lands at next iteration's LDS write -> latency hidden

    __syncthreads();    // the ONLY barrier per step: vb complete before dots

    // wave wv: 4 gate rows (i,f,g,o of its unit), full-wave dots, v reused
    float4 v0 = *(const float4*)&vb[lane4];
    float4 v1 = *(const float4*)&vb[256 + lane4];
    float4 v2 = *(const float4*)&vb[512 + lane4];
    float4 v3 = *(const float4*)&vb[768 + lane4];
    float acc[4];
#pragma unroll
    for (int g = 0; g < 4; ++g) {
      const float* wr = lds_W + (wv * 4 + g) * RS + lane4;
      float4 w0 = *(const float4*)(wr);
      float4 w1 = *(const float4*)(wr + 256);
      float4 w2 = *(const float4*)(wr + 512);
      float4 w3 = *(const float4*)(wr + 768);
      float s;
      s = w0.x * v0.x;         s = fmaf(w0.y, v0.y, s);
      s = fmaf(w0.z, v0.z, s); s = fmaf(w0.w, v0.w, s);
      s = fmaf(w1.x, v1.x, s); s = fmaf(w1.y, v1.y, s);
      s = fmaf(w1.z, v1.z, s); s = fmaf(w1.w, v1.w, s);
      s = fmaf(w2.x, v2.x, s); s = fmaf(w2.y, v2.y, s);
      s = fmaf(w2.z, v2.z, s); s = fmaf(w2.w, v2.w, s);
      s = fmaf(w3.x, v3.x, s); s = fmaf(w3.y, v3.y, s);
      s = fmaf(w3.z, v3.z, s); s = fmaf(w3.w, v3.w, s);
      acc[g] = s;
    }
#pragma unroll
    for (int g = 0; g < 4; ++g) {
      acc[g] += __shfl_xor(acc[g], 1);
      acc[g] += __shfl_xor(acc[g], 2);
    }
    const int sel = lane & 3;
    float s = (sel == 0) ? acc[0] : (sel == 1) ? acc[1] : (sel == 2) ? acc[2] : acc[3];
    s += __shfl_xor(s, 4);  s += __shfl_xor(s, 8);
    s += __shfl_xor(s, 16); s += __shfl_xor(s, 32);

    float pre = (sel == 2) ? 2.f * s : s;
    float sg  = 1.f / (1.f + __expf(-pre));
    float act = (sel == 2) ? (2.f * sg - 1.f) : sg;   // tanh(s) = 2*sig(2s)-1
    float a_i = __shfl(act, 0);
    float a_f = __shfl(act, 1);
    float a_g = __shfl(act, 2);
    float a_o = __shfl(act, 3);

    if (lane == 0) {
      c_state  = fmaf(a_f, c_state, a_i * a_g);
      float ac = fabsf(c_state);
      float e  = __expf(-2.f * ac);                   // overflow-safe tanh
      float th = (1.f - e) / (1.f + e);
      th = copysignf(th, c_state);
      float hv = a_o * th;
      ag_store(ent + (t & 1) * EPAR + (size_t)(4 * bid + wv),
               pack_entry(hv, (uint32)t));            // publish immediately
    }
    // no trailing barrier: next step writes the OTHER lds_v buffer; the
    // pre-dot barrier of step t+1 protects buffer reuse at t+2.
  }

  // -------- MLP: 4 rounds, wave wv computes unit 4*bid+wv -----------------------
  for (int r = 1; r <= 4; ++r) {
    const uint32 sprev = (uint32)(T_STEPS + r - 1);
    float* vb = lds_v[sprev & 1];
    gather_dense(ent + (sprev & 1) * EPAR, sprev, tid, vb, /*relu h_T*/ (r == 1));
    __syncthreads();

    const float* WL  = (r == 1) ? W1 : (r == 2) ? W2 : (r == 3) ? W3 : W4;
    const float* bLp = (r == 1) ? b1 : (r == 2) ? b2 : (r == 3) ? b3 : b4;
    const int u = 4 * bid + wv;
    const float* row = WL + (size_t)u * HID;

    float4 v0 = *(const float4*)&vb[lane4];
    float4 v1 = *(const float4*)&vb[256 + lane4];
    float4 v2 = *(const float4*)&vb[512 + lane4];
    float4 v3 = *(const float4*)&vb[768 + lane4];
    float4 w0 = *(const float4*)(row + lane4);
    float4 w1 = *(const float4*)(row + 256 + lane4);
    float4 w2 = *(const float4*)(row + 512 + lane4);
    float4 w3 = {0.f, 0.f, 0.f, 0.f};
    if (lane < 58) w3 = *(const float4*)(row + 768 + lane4);  // floats [768,1000)

    float s;
    s = w0.x * v0.x;         s = fmaf(w0.y, v0.y, s);
    s = fmaf(w0.z, v0.z, s); s = fmaf(w0.w, v0.w, s);
    s = fmaf(w1.x, v1.x, s); s = fmaf(w1.y, v1.y, s);
    s = fmaf(w1.z, v1.z, s); s = fmaf(w1.w, v1.w, s);
    s = fmaf(w2.x, v2.x, s); s = fmaf(w2.y, v2.y, s);
    s = fmaf(w2.z, v2.z, s); s = fmaf(w2.w, v2.w, s);
    s = fmaf(w3.x, v3.x, s); s = fmaf(w3.y, v3.y, s);
    s = fmaf(w3.z, v3.z, s); s = fmaf(w3.w, v3.w, s);
    s += __shfl_xor(s, 1);  s += __shfl_xor(s, 2);  s += __shfl_xor(s, 4);
    s += __shfl_xor(s, 8);  s += __shfl_xor(s, 16); s += __shfl_xor(s, 32);

    if (lane == 0) {
      float y = fmaxf(s + bLp[u], 0.f);
      ag_store(ent + ((T_STEPS + r) & 1) * EPAR + (size_t)u,
               pack_entry(y, (uint32)(T_STEPS + r)));
    }
    // next round's gather targets the other parity buffer; barrier there suffices
  }

  // -------- final: WG0 computes logits + softmax --------------------------------
  if (bid == 0) {
    const uint32 sfin = (uint32)(T_STEPS + 4);
    float* vb = lds_v[sfin & 1];
    gather_dense(ent + (sfin & 1) * EPAR, sfin, tid, vb, false);
    __syncthreads();

    float s = 0.f;
    if (wv < 3) {
      const float* row = Wo + (size_t)wv * HID;
      float4 v0 = *(const float4*)&vb[lane4];
      float4 v1 = *(const float4*)&vb[256 + lane4];
      float4 v2 = *(const float4*)&vb[512 + lane4];
      float4 v3 = *(const float4*)&vb[768 + lane4];
      float4 w0 = *(const float4*)(row + lane4);
      float4 w1 = *(const float4*)(row + 256 + lane4);
      float4 w2 = *(const float4*)(row + 512 + lane4);
      float4 w3 = {0.f, 0.f, 0.f, 0.f};
      if (lane < 58) w3 = *(const float4*)(row + 768 + lane4);
      s = w0.x * v0.x;         s = fmaf(w0.y, v0.y, s);
      s = fmaf(w0.z, v0.z, s); s = fmaf(w0.w, v0.w, s);
      s = fmaf(w1.x, v1.x, s); s = fmaf(w1.y, v1.y, s);
      s = fmaf(w1.z, v1.z, s); s = fmaf(w1.w, v1.w, s);
      s = fmaf(w2.x, v2.x, s); s = fmaf(w2.y, v2.y, s);
      s = fmaf(w2.z, v2.z, s); s = fmaf(w2.w, v2.w, s);
      s = fmaf(w3.x, v3.x, s); s = fmaf(w3.z, v3.z, s);
      s = fmaf(w3.y, v3.y, s); s = fmaf(w3.w, v3.w, s);
      s += __shfl_xor(s, 1);  s += __shfl_xor(s, 2);  s += __shfl_xor(s, 4);
      s += __shfl_xor(s, 8);  s += __shfl_xor(s, 16); s += __shfl_xor(s, 32);
    }
    if (wv < 3 && lane == 0) lds_log[wv] = s + bo[wv];
    __syncthreads();
    if (tid == 0) {
      float l0 = lds_log[0], l1 = lds_log[1], l2 = lds_log[2];
      float m  = fmaxf(l0, fmaxf(l1, l2));
      float e0 = __expf(l0 - m), e1 = __expf(l1 - m), e2 = __expf(l2 - m);
      float inv = 1.f / (e0 + e1 + e2);
      out[0] = e0 * inv; out[1] = e1 * inv; out[2] = e2 * inv;
    }
  }
}

extern "C" void kernel_launch(void* const* d_in, const int* in_sizes, int n_in,
                              void* d_out, int out_size, void* d_ws, size_t ws_size,
                              hipStream_t stream) {
  const float* x    = (const float*)d_in[0];
  const float* h0   = (const float*)d_in[1];
  const float* c0   = (const float*)d_in[2];
  const float* W_ih = (const float*)d_in[3];
  const float* W_hh = (const float*)d_in[4];
  const float* b_ih = (const float*)d_in[5];
  const float* b_hh = (const float*)d_in[6];
  const float* W1 = (const float*)d_in[7];
  const float* b1 = (const float*)d_in[8];
  const float* W2 = (const float*)d_in[9];
  const float* b2 = (const float*)d_in[10];
  const float* W3 = (const float*)d_in[11];
  const float* b3 = (const float*)d_in[12];
  const float* W4 = (const float*)d_in[13];
  const float* b4 = (const float*)d_in[14];
  const float* Wo = (const float*)d_in[15];
  const float* bo = (const float*)d_in[16];

  u64* ent = (u64*)d_ws;   // dense: 2 parities x 1024 u64 {val lo32, seq hi32}

  // seqs must start at 0 every launch (graph replays reuse the same workspace)
  hipMemsetAsync(ent, 0, 2 * EPAR * sizeof(u64), stream);

  // +12KB dynamic LDS: static ~73KB -> ~85KB total, forces 1 WG/CU (250 WGs spread)
  hipLaunchKernelGGL(lstm_mlp_kernel, dim3(NB), dim3(NTH), 12288, stream,
                     x, h0, c0, W_ih, W_hh, b_ih, b_hh,
                     W1, b1, W2, b2, W3, b3, W4, b4, Wo, bo,
                     ent, (float*)d_out);
}

// Round 7
// 61206.616 us; speedup vs baseline: 1.0568x; 1.0568x over previous
//
#include <hip/hip_runtime.h>

#define T_STEPS 16384
#define HID     1000
#define NB      63       // WGs; WG b owns units [16b, 16b+16) ∩ [0,1000)
#define NTH     512      // 8 waves; wave w owns units 16b+2w, 16b+2w+1
#define EPAR    1024     // u64 entries per parity buffer (1000 used)

typedef unsigned int       uint32;
typedef unsigned long long u64;

__device__ __forceinline__ u64 ag_load(const u64* p) {
  return __hip_atomic_load(p, __ATOMIC_RELAXED, __HIP_MEMORY_SCOPE_AGENT);
}
__device__ __forceinline__ void ag_store(u64* p, u64 v) {
  __hip_atomic_store(p, v, __ATOMIC_RELAXED, __HIP_MEMORY_SCOPE_AGENT);
}
__device__ __forceinline__ u64 pack_entry(float v, uint32 seq) {
  return ((u64)seq << 32) | (u64)__float_as_uint(v);
}

// Poll entries {2*tid, 2*tid+1} (dense {val lo32, seq hi32}) until seq==tgt,
// write values (optionally relu'd) into vb. Immediate re-poll, no sleep.
// Terminates by the 2-parity induction: seq can only advance to tgt+2 after
// every WG (all are producers) has consumed tgt.
__device__ __forceinline__ void gather_pair(const u64* ep, uint32 tgt, int tid,
                                            float* vb, bool relu) {
  if (tid >= 500) return;
  uint32 pend = 3u;
  u64 ea = 0, eb = 0;
  do {
    if (pend & 1u) ea = ag_load(ep + 2 * tid);
    if (pend & 2u) eb = ag_load(ep + 2 * tid + 1);
    if ((pend & 1u) && (uint32)(ea >> 32) == tgt) {
      float v = __uint_as_float((uint32)ea);
      vb[2 * tid] = relu ? fmaxf(v, 0.f) : v;
      pend &= ~1u;
    }
    if ((pend & 2u) && (uint32)(eb >> 32) == tgt) {
      float v = __uint_as_float((uint32)eb);
      vb[2 * tid + 1] = relu ? fmaxf(v, 0.f) : v;
      pend &= ~2u;
    }
  } while (pend);
}

__global__ __launch_bounds__(NTH, 2) void lstm_mlp_kernel(
    const float* __restrict__ x,    const float* __restrict__ h0,
    const float* __restrict__ c0,   const float* __restrict__ W_ih,
    const float* __restrict__ W_hh, const float* __restrict__ b_ih,
    const float* __restrict__ b_hh,
    const float* __restrict__ W1, const float* __restrict__ b1,
    const float* __restrict__ W2, const float* __restrict__ b2,
    const float* __restrict__ W3, const float* __restrict__ b3,
    const float* __restrict__ W4, const float* __restrict__ b4,
    const float* __restrict__ Wo, const float* __restrict__ bo,
    u64* __restrict__ ent, float* __restrict__ out)
{
  __shared__ __align__(16) float lds_v[2][1024];  // [h(1000) | x(18) | 1.0 | 0 x5]
  __shared__ float lds_log[3];

  const int tid  = threadIdx.x;
  const int bid  = blockIdx.x;
  const int wv   = tid >> 6;      // wave 0..7
  const int lane = tid & 63;
  const int u0   = 16 * bid + 2 * wv;   // this wave's units: u0, u0+1

  // -------- W into REGISTERS: 8 rows (2 units x 4 gates) x 16 cols/lane --------
  // Column map: lane l holds cols {l + 64q, q=0..15} of the extended 1024-row
  // [W_hh(1000) | W_ih(18) | b_ih+b_hh(1) | 0 x5].  q<15 -> col<960: pure W_hh.
  float wreg[2][4][16];
#pragma unroll
  for (int j = 0; j < 2; ++j) {
    const int  u    = u0 + j;
    const bool real = (u < HID);               // wave-uniform
    const int  gr0  = real ? u : 0;
#pragma unroll
    for (int g = 0; g < 4; ++g) {
      const int grow = g * HID + gr0;
      const float* src = W_hh + (size_t)grow * HID;
      if (real) {
#pragma unroll
        for (int q = 0; q < 15; ++q)
          wreg[j][g][q] = src[lane + 64 * q];   // coalesced: 64 consecutive floats
        const int col = 960 + lane;             // q=15: mixed tail
        float vq;
        if      (col < HID)  vq = src[col];
        else if (col < 1018) vq = W_ih[(size_t)grow * 18 + (col - 1000)];
        else if (col == 1018) vq = b_ih[grow] + b_hh[grow];
        else                 vq = 0.f;
        wreg[j][g][15] = vq;
      } else {
#pragma unroll
        for (int q = 0; q < 16; ++q) wreg[j][g][q] = 0.f;
      }
    }
  }

  // c state: lane 0 carries unit u0, lane 4 carries unit u0+1
  float c_state = 0.f;
  {
    const int uj = u0 + ((lane >> 2) & 1);
    if (uj < HID) c_state = c0[uj];
  }

  if (tid < 24) {                               // fixed tails of both v buffers
    const float z = (tid == 18) ? 1.f : 0.f;
    lds_v[0][1000 + tid] = z;
    lds_v[1][1000 + tid] = z;
  }
  float xval = (tid < 18) ? x[tid] : 0.f;       // x for step 1
  __syncthreads();

  // -------- 16384-step recurrence ----------------------------------------------
  for (int t = 1; t <= T_STEPS; ++t) {
    float* vb = lds_v[(t - 1) & 1];
    if (tid < 18) vb[1000 + tid] = xval;

    if (t == 1) {
      if (tid < 500) *(float2*)&vb[2 * tid] = *(const float2*)&h0[2 * tid];
    } else {
      gather_pair(ent + ((t - 1) & 1) * EPAR, (uint32)(t - 1), tid, vb, false);
    }
    if (tid < 18 && t < T_STEPS) xval = x[(size_t)t * 18 + tid];  // prefetch next
    __syncthreads();   // the one barrier per step

    // v chunk to registers: 16 reads, 2 lanes/bank (conflict-free per m136)
    float vreg[16];
#pragma unroll
    for (int q = 0; q < 16; ++q) vreg[q] = vb[lane + 64 * q];

    // 8 register-resident row dots
    float acc[2][4];
#pragma unroll
    for (int j = 0; j < 2; ++j)
#pragma unroll
      for (int g = 0; g < 4; ++g) {
        float s = 0.f;
#pragma unroll
        for (int q = 0; q < 16; ++q) s = fmaf(wreg[j][g][q], vreg[q], s);
        acc[j][g] = s;
      }
    // phase A: reduce each acc within 8-lane groups
#pragma unroll
    for (int j = 0; j < 2; ++j)
#pragma unroll
      for (int g = 0; g < 4; ++g) {
        float a = acc[j][g];
        a += __shfl_xor(a, 1); a += __shfl_xor(a, 2); a += __shfl_xor(a, 4);
        acc[j][g] = a;
      }
    // phase B: lane sel picks its (unit, gate), reduce across the 8 groups
    const int sel = lane & 7;
    float s = (sel == 0) ? acc[0][0] : (sel == 1) ? acc[0][1] :
              (sel == 2) ? acc[0][2] : (sel == 3) ? acc[0][3] :
              (sel == 4) ? acc[1][0] : (sel == 5) ? acc[1][1] :
              (sel == 6) ? acc[1][2] : acc[1][3];
    s += __shfl_xor(s, 8); s += __shfl_xor(s, 16); s += __shfl_xor(s, 32);

    const int gg  = sel & 3;
    float pre = (gg == 2) ? 2.f * s : s;
    float sg  = 1.f / (1.f + __expf(-pre));
    float act = (gg == 2) ? (2.f * sg - 1.f) : sg;   // tanh(s) = 2*sig(2s)-1
    const int base = lane & 4;
    float a_i = __shfl(act, base);
    float a_f = __shfl(act, base + 1);
    float a_g = __shfl(act, base + 2);
    float a_o = __shfl(act, base + 3);

    const int uj = u0 + ((lane >> 2) & 1);
    if ((lane & 3) == 0 && lane < 8 && uj < HID) {   // lanes 0 and 4 publish
      c_state  = fmaf(a_f, c_state, a_i * a_g);
      float ac = fabsf(c_state);
      float e  = __expf(-2.f * ac);                  // overflow-safe tanh
      float th = (1.f - e) / (1.f + e);
      th = copysignf(th, c_state);
      float hv = a_o * th;
      ag_store(ent + (t & 1) * EPAR + uj, pack_entry(hv, (uint32)t));
    }
    // no trailing barrier: next step uses the other v buffer; its pre-dot
    // barrier protects reuse at t+2 (all waves passed t+1's barrier => done with t's dot)
  }

  // -------- MLP: 4 rounds; wave wv computes units u0, u0+1 ----------------------
  for (int r = 1; r <= 4; ++r) {
    const uint32 sprev = (uint32)(T_STEPS + r - 1);
    float* vb = lds_v[sprev & 1];
    gather_pair(ent + (sprev & 1) * EPAR, sprev, tid, vb, /*relu h_T*/ (r == 1));
    __syncthreads();

    const float* WL  = (r == 1) ? W1 : (r == 2) ? W2 : (r == 3) ? W3 : W4;
    const float* bLp = (r == 1) ? b1 : (r == 2) ? b2 : (r == 3) ? b3 : b4;

    float accm[2] = {0.f, 0.f};
#pragma unroll
    for (int j = 0; j < 2; ++j) {
      const int u = u0 + j;
      if (u < HID) {                              // wave-uniform branch
        const float* row = WL + (size_t)u * HID;
        float s = 0.f;
#pragma unroll
        for (int q = 0; q < 15; ++q) {
          const int col = lane + 64 * q;
          s = fmaf(row[col], vb[col], s);         // coalesced global reads
        }
        const int col = 960 + lane;
        if (col < HID) s = fmaf(row[col], vb[col], s);
        accm[j] = s;
      }
    }
#pragma unroll
    for (int j = 0; j < 2; ++j) {
      float a = accm[j];
      a += __shfl_xor(a, 1);  a += __shfl_xor(a, 2);  a += __shfl_xor(a, 4);
      a += __shfl_xor(a, 8);  a += __shfl_xor(a, 16); a += __shfl_xor(a, 32);
      accm[j] = a;
    }
    if (lane == 0) {
#pragma unroll
      for (int j = 0; j < 2; ++j) {
        const int u = u0 + j;
        if (u < HID) {
          float y = fmaxf(accm[j] + bLp[u], 0.f);
          ag_store(ent + ((T_STEPS + r) & 1) * EPAR + u,
                   pack_entry(y, (uint32)(T_STEPS + r)));
        }
      }
    }
    __syncthreads();   // vb reused by next round's gather only after all waves done
  }

  // -------- final: WG0 computes logits + softmax --------------------------------
  if (bid == 0) {
    const uint32 sfin = (uint32)(T_STEPS + 4);
    float* vb = lds_v[sfin & 1];
    gather_pair(ent + (sfin & 1) * EPAR, sfin, tid, vb, false);
    __syncthreads();

    if (wv < 3) {
      const float* row = Wo + (size_t)wv * HID;
      float s = 0.f;
#pragma unroll
      for (int q = 0; q < 15; ++q) {
        const int col = lane + 64 * q;
        s = fmaf(row[col], vb[col], s);
      }
      const int col = 960 + lane;
      if (col < HID) s = fmaf(row[col], vb[col], s);
      s += __shfl_xor(s, 1);  s += __shfl_xor(s, 2);  s += __shfl_xor(s, 4);
      s += __shfl_xor(s, 8);  s += __shfl_xor(s, 16); s += __shfl_xor(s, 32);
      if (lane == 0) lds_log[wv] = s + bo[wv];
    }
    __syncthreads();
    if (tid == 0) {
      float l0 = lds_log[0], l1 = lds_log[1], l2 = lds_log[2];
      float m  = fmaxf(l0, fmaxf(l1, l2));
      float e0 = __expf(l0 - m), e1 = __expf(l1 - m), e2 = __expf(l2 - m);
      float inv = 1.f / (e0 + e1 + e2);
      out[0] = e0 * inv; out[1] = e1 * inv; out[2] = e2 * inv;
    }
  }
}

extern "C" void kernel_launch(void* const* d_in, const int* in_sizes, int n_in,
                              void* d_out, int out_size, void* d_ws, size_t ws_size,
                              hipStream_t stream) {
  const float* x    = (const float*)d_in[0];
  const float* h0   = (const float*)d_in[1];
  const float* c0   = (const float*)d_in[2];
  const float* W_ih = (const float*)d_in[3];
  const float* W_hh = (const float*)d_in[4];
  const float* b_ih = (const float*)d_in[5];
  const float* b_hh = (const float*)d_in[6];
  const float* W1 = (const float*)d_in[7];
  const float* b1 = (const float*)d_in[8];
  const float* W2 = (const float*)d_in[9];
  const float* b2 = (const float*)d_in[10];
  const float* W3 = (const float*)d_in[11];
  const float* b3 = (const float*)d_in[12];
  const float* W4 = (const float*)d_in[13];
  const float* b4 = (const float*)d_in[14];
  const float* Wo = (const float*)d_in[15];
  const float* bo = (const float*)d_in[16];

  u64* ent = (u64*)d_ws;   // dense: 2 parities x 1024 u64 {val lo32, seq hi32}

  // seqs must start at 0 every launch (graph replays reuse the same workspace)
  hipMemsetAsync(ent, 0, 2 * EPAR * sizeof(u64), stream);

  // 63 WGs, 8 waves, ~200 VGPR (W in registers) -> 1 WG/CU, all co-resident
  hipLaunchKernelGGL(lstm_mlp_kernel, dim3(NB), dim3(NTH), 0, stream,
                     x, h0, c0, W_ih, W_hh, b_ih, b_hh,
                     W1, b1, W2, b2, W3, b3, W4, b4, Wo, bo,
                     ent, (float*)d_out);
}